// Round 3
// baseline (356.389 us; speedup 1.0000x reference)
//
#include <hip/hip_runtime.h>
#include <math.h>

#define B 2
#define CH 128
#define H 96
#define W 128
#define HP 104
#define WP 136
#define KPAD 4
#define NSHIFT 81
#define NBR 6
#define HW (H*W)         // 12288
#define HWP (HP*WP)      // 14144
#define NTILE 111        // ceil(14144/128)
#define NWORK (NTILE*12) // 1332
#define NBLK  (8*167)    // 1336 (>= NWORK, 8-way XCD chunking)

typedef _Float16 h2 __attribute__((ext_vector_type(2)));
typedef _Float16 half8 __attribute__((ext_vector_type(8)));
typedef float floatx4 __attribute__((ext_vector_type(4)));

__device__ __constant__ int d_radius[NBR] = {1, 3, 5, 9, 13, 21};

__device__ __forceinline__ void async16(const _Float16* g, _Float16* l) {
    __builtin_amdgcn_global_load_lds(
        (const __attribute__((address_space(1))) unsigned int*)g,
        (__attribute__((address_space(3))) unsigned int*)l, 16, 0, 0);
}

// ---------------------------------------------------------------------------
// y[b][c][hw] (f32) -> yt16[b][hw][c] (f16) channels-last, via LDS transpose.
__global__ __launch_bounds__(256) void prep_y(const float* __restrict__ y,
                                              _Float16* __restrict__ yt16) {
    __shared__ h2 tile[64 * 129];   // [c2][pix], padded stride 129 dwords
    const int tid = threadIdx.x;
    const int b = blockIdx.y;
    const int pix0 = blockIdx.x * 128;
    const int half = tid >> 7;       // 0/1 -> channel half
    const int pl = tid & 127;        // pixel lane

    const float* yb = y + (size_t)b * CH * HW + pix0 + pl;
    #pragma unroll
    for (int k = 0; k < 32; ++k) {
        int c = half * 64 + 2 * k;
        float v0 = yb[(size_t)c * HW];
        float v1 = yb[(size_t)(c + 1) * HW];
        h2 v; v[0] = (_Float16)v0; v[1] = (_Float16)v1;
        tile[(half * 32 + k) * 129 + pl] = v;
    }
    __syncthreads();

    _Float16* ob = yt16 + ((size_t)b * HW + pix0) * CH;
    #pragma unroll
    for (int it = 0; it < 8; ++it) {
        int pix = it * 16 + (tid >> 4);
        int c2b = (tid & 15) * 4;          // h2 index base
        h2 t0 = tile[(c2b + 0) * 129 + pix];
        h2 t1 = tile[(c2b + 1) * 129 + pix];
        h2 t2 = tile[(c2b + 2) * 129 + pix];
        h2 t3 = tile[(c2b + 3) * 129 + pix];
        half8 o;
        o[0] = t0[0]; o[1] = t0[1]; o[2] = t1[0]; o[3] = t1[1];
        o[4] = t2[0]; o[5] = t2[1]; o[6] = t3[0]; o[7] = t3[1];
        *(half8*)(ob + (size_t)pix * CH + (tid & 15) * 8) = o;
    }
}

// weights[br][co][ci][tap] (f32) -> w16t[br][tap][co][ci] (f16); also zero zbuf
__global__ __launch_bounds__(256) void convert_w_kernel(const float* __restrict__ w,
                                                        _Float16* __restrict__ w16t,
                                                        _Float16* __restrict__ zbuf) {
    int gid = blockIdx.x * 256 + threadIdx.x;
    if (gid < 256) zbuf[gid] = (_Float16)0.0f;
    if (gid >= NBR * 9 * CH * CH) return;
    int ci = gid & 127;
    int co = (gid >> 7) & 127;
    int rest = gid >> 14;       // br*9 + tap
    int tap = rest % 9;
    int br = rest / 9;
    w16t[gid] = (_Float16)w[(((size_t)(br * CH + co)) * CH + ci) * 9 + tap];
}

// x[b][c][hw] f32 -> xh[b][g][pair][hw] half2 AND xn[b][g][hw] (fused, 1 pass).
__global__ __launch_bounds__(256) void prep_x(const float* __restrict__ x,
                                              h2* __restrict__ xh,
                                              float* __restrict__ xn) {
    const int b = blockIdx.y;
    const int pix = blockIdx.x * 256 + threadIdx.x;
    const float* xb = x + (size_t)b * CH * HW + pix;
    #pragma unroll
    for (int g = 0; g < 4; ++g) {
        float s = 0.f;
        #pragma unroll
        for (int p = 0; p < 16; ++p) {
            int c = g * 32 + 2 * p;
            float v0 = xb[(size_t)c * HW];
            float v1 = xb[(size_t)(c + 1) * HW];
            h2 v; v[0] = (_Float16)v0; v[1] = (_Float16)v1;
            xh[((size_t)((b * 4 + g) * 16 + p)) * HW + pix] = v;
            s += v0 * v0 + v1 * v1;
        }
        xn[(size_t)(b * 4 + g) * HW + pix] = sqrtf(s);
    }
}

// ---------------------------------------------------------------------------
// Implicit-GEMM dilated conv, f16 MFMA. 128 co x 128 pixels per block.
// Depth-2 counted-vmcnt pipeline (T4): 3 LDS buffers, per step
//   s_waitcnt vmcnt(4) -> s_barrier -> issue(s+2) -> ds_read(s) -> 16 MFMA.
// XCD-chunked 1D grid (T1): each XCD owns ~14 contiguous pixel tiles x all
// (br,b), so its yt16 working set (~3.5 MB) fits the 4 MB per-XCD L2.
// Writes ygh (bias added) AND fused yn_all.
__global__ __launch_bounds__(256) void conv_mfma(const _Float16* __restrict__ yt16,
                                                 const _Float16* __restrict__ w16t,
                                                 const _Float16* __restrict__ zbuf,
                                                 const float* __restrict__ biases,
                                                 h2* __restrict__ ygh,
                                                 float* __restrict__ yn_all) {
    const int f = blockIdx.x;
    const int Wk = (f & 7) * 167 + (f >> 3);
    if (Wk >= NWORK) return;
    const int tile = Wk / 12;
    const int brb = Wk - tile * 12;
    const int br = brb >> 1;
    const int b = brb & 1;

    const int tid = threadIdx.x;
    const int lane = tid & 63;
    const int wv = tid >> 6;
    const int d = d_radius[br];
    const int px0 = tile * 128;

    __shared__ __align__(16) _Float16 Al[3][128 * 32];
    __shared__ __align__(16) _Float16 Bl[3][128 * 32];

    const int l16 = tid & 3;
    int ph[2], pw[2];
    bool pval[2];
    #pragma unroll
    for (int s = 0; s < 2; ++s) {
        int pixl = s * 64 + (tid >> 2);
        int pix = px0 + pixl;
        pval[s] = pix < HWP;
        int phh = pix / WP;
        ph[s] = phh; pw[s] = pix - phh * WP;
    }

    const _Float16* ytb = yt16 + (size_t)b * HW * CH;
    const _Float16* wbr = w16t + (size_t)br * 9 * CH * CH;

    floatx4 acc[4][4];
    #pragma unroll
    for (int i = 0; i < 4; i++)
        #pragma unroll
        for (int j = 0; j < 4; j++) {
            floatx4 z = {0.f, 0.f, 0.f, 0.f};
            acc[i][j] = z;
        }

    const int mrow = (wv & 1) * 64 + (lane & 15);
    const int ncol = (wv >> 1) * 64 + (lane & 15);
    const int kq = (lane >> 4) * 8;

    const _Float16* bt0; const _Float16* bt1;   // B rows for the tap being ISSUED
    auto comp_brow = [&](int tap) {
        const int dkh = (tap / 3 - 1) * d;
        const int dkw = (tap % 3 - 1) * d;
        const _Float16* bw[2];
        #pragma unroll
        for (int s = 0; s < 2; ++s) {
            int gr = ph[s] + dkh, gc = pw[s] + dkw;
            bool v = pval[s] && ((unsigned)gr < (unsigned)HP) && ((unsigned)gc < (unsigned)WP);
            if (v) {
                int yr = gr - KPAD; yr = yr < 0 ? -yr : (yr >= H ? 2 * (H - 1) - yr : yr);
                int yc = gc - KPAD; yc = yc < 0 ? -yc : (yc >= W ? 2 * (W - 1) - yc : yc);
                bw[s] = ytb + ((size_t)(yr * W + yc)) * CH + l16 * 8;
            } else {
                bw[s] = zbuf + l16 * 8;
            }
        }
        bt0 = bw[0]; bt1 = bw[1];
    };

    const _Float16* wa0 = wbr + (tid >> 2) * CH + l16 * 8;
    auto issue = [&](int t, int bufi) {
        const int tap = t >> 2, ck = t & 3;
        const int ci0 = ck * 32;
        const _Float16* wa = wa0 + tap * (CH * CH) + ci0;
        async16(wa,           Al[bufi] + wv * 512);
        async16(wa + 64 * CH, Al[bufi] + 2048 + wv * 512);
        async16(bt0 + ci0,    Bl[bufi] + wv * 512);
        async16(bt1 + ci0,    Bl[bufi] + 2048 + wv * 512);
    };

    auto compute = [&](int bufi) {
        half8 af[4], bf[4];
        #pragma unroll
        for (int i = 0; i < 4; i++) af[i] = *(const half8*)&Al[bufi][(mrow + i * 16) * 32 + kq];
        #pragma unroll
        for (int j = 0; j < 4; j++) bf[j] = *(const half8*)&Bl[bufi][(ncol + j * 16) * 32 + kq];
        #pragma unroll
        for (int i = 0; i < 4; i++)
            #pragma unroll
            for (int j = 0; j < 4; j++)
                acc[i][j] = __builtin_amdgcn_mfma_f32_16x16x32_f16(af[i], bf[j], acc[i][j], 0, 0, 0);
    };

    // prologue: issue steps 0 and 1
    comp_brow(0);
    issue(0, 0);
    issue(1, 1);

    int bufc = 0;
    for (int s = 0; s < 35; ++s) {
        asm volatile("s_waitcnt vmcnt(4)" ::: "memory");
        __builtin_amdgcn_s_barrier();
        __builtin_amdgcn_sched_barrier(0);
        const int t2 = s + 2;
        if (t2 < 36) {
            if ((t2 & 3) == 0) comp_brow(t2 >> 2);
            int bn = bufc + 2; if (bn >= 3) bn -= 3;
            issue(t2, bn);
        }
        compute(bufc);
        bufc = (bufc == 2) ? 0 : bufc + 1;
    }
    // last step: drain fully
    asm volatile("s_waitcnt vmcnt(0)" ::: "memory");
    __builtin_amdgcn_s_barrier();
    __builtin_amdgcn_sched_barrier(0);
    compute(bufc);

    // epilogue: bias + pack to half2 pairs. C layout: n=lane&15, m=(lane>>4)*4+reg
    float yna[2][4];
    #pragma unroll
    for (int gs = 0; gs < 2; ++gs)
        #pragma unroll
        for (int j = 0; j < 4; ++j) yna[gs][j] = 0.f;

    #pragma unroll
    for (int i = 0; i < 4; i++) {
        int m0 = (wv & 1) * 64 + i * 16 + (lane >> 4) * 4;   // multiple of 4
        int g0 = (m0 >> 5);
        int pp = (m0 & 31) >> 1;
        float b0 = biases[br * CH + m0];
        float b1 = biases[br * CH + m0 + 1];
        float b2 = biases[br * CH + m0 + 2];
        float b3 = biases[br * CH + m0 + 3];
        h2* outp = ygh + (((size_t)(br * B + b) * 4 + g0) * 16 + pp) * HWP;
        #pragma unroll
        for (int j = 0; j < 4; j++) {
            int pix = px0 + (wv >> 1) * 64 + j * 16 + (lane & 15);
            if (pix < HWP) {
                float f0 = acc[i][j][0] + b0;
                float f1 = acc[i][j][1] + b1;
                float f2 = acc[i][j][2] + b2;
                float f3 = acc[i][j][3] + b3;
                yna[i >> 1][j] += f0 * f0 + f1 * f1 + f2 * f2 + f3 * f3;
                h2 v0, v1;
                v0[0] = (_Float16)f0;
                v0[1] = (_Float16)f1;
                v1[0] = (_Float16)f2;
                v1[1] = (_Float16)f3;
                outp[pix] = v0;
                outp[(size_t)HWP + pix] = v1;
            }
        }
    }

    #pragma unroll
    for (int gs = 0; gs < 2; ++gs) {
        #pragma unroll
        for (int j = 0; j < 4; ++j) {
            float s = yna[gs][j];
            s += __shfl_xor(s, 16);
            s += __shfl_xor(s, 32);
            if ((lane >> 4) == 0) {
                int pix = px0 + (wv >> 1) * 64 + j * 16 + lane;
                if (pix < HWP) {
                    int g = (wv & 1) * 2 + gs;
                    yn_all[((size_t)((br * B + b) * 4 + g)) * HWP + pix] = sqrtf(s);
                }
            }
        }
    }
}

// ---------------------------------------------------------------------------
// Correlation: chunk dim in the grid (1728 blocks), double-buffered staging
// with prefetch-before-compute. Grid: (12, 8, NBR*3)
#define CPAIR 4
__global__ __launch_bounds__(256) void corr2_kernel(const h2* __restrict__ xh,
                                                    const h2* __restrict__ ygh,
                                                    const float* __restrict__ xn,
                                                    const float* __restrict__ yn_all,
                                                    float* __restrict__ out) {
    const int tid = threadIdx.x;
    const int row = tid >> 5;          // 0..7
    const int col4 = (tid & 31) * 4;   // 0..124
    const int H0 = blockIdx.x * 8;
    const int bg = blockIdx.y;
    const int g = bg & 3, b = bg >> 2;
    const int brl = blockIdx.z / 3;
    const int chunk = blockIdx.z - brl * 3;
    const int hh = H0 + row;
    const int row0 = H0 + chunk * 3;

    __shared__ __align__(16) _Float16 yt[2][CPAIR * 340 * 8];   // 2 x 21760 B

    const h2* ygb = ygh + ((size_t)((brl * B + b) * 4 + g) * 16) * HWP;
    const h2* xb  = xh  + ((size_t)(b * 4 + g) * 16) * HW;
    const float* ynb = yn_all + (size_t)((brl * B + b) * 4 + g) * HWP;

    float xnv[4];
    *(floatx4*)xnv = *(const floatx4*)(xn + (size_t)(b * 4 + g) * HW + hh * W + col4);

    float acc[108];
    #pragma unroll
    for (int s = 0; s < 108; ++s) acc[s] = 0.f;

    // prologue: stage pairs [0,CPAIR) into buffer 0
    for (int i = tid; i < CPAIR * 340; i += 256) {
        int pr = i / 340, off = i - pr * 340;
        const _Float16* src =
            (const _Float16*)(ygb + (size_t)pr * HWP + row0 * WP) + off * 8;
        async16(src, yt[0] + i * 8);
    }
    __syncthreads();

    #pragma unroll
    for (int pi = 0; pi < 4; ++pi) {
        const int cur = pi & 1;
        if (pi < 3) {
            const int p0n = (pi + 1) * CPAIR;
            for (int i = tid; i < CPAIR * 340; i += 256) {
                int pr = i / 340, off = i - pr * 340;
                const _Float16* src =
                    (const _Float16*)(ygb + (size_t)(p0n + pr) * HWP + row0 * WP) + off * 8;
                async16(src, yt[cur ^ 1] + i * 8);
            }
        }
        const int p0 = pi * CPAIR;
        #pragma unroll
        for (int cp = 0; cp < CPAIR; ++cp) {
            h2 x2[4];
            *(half8*)x2 = *(const half8*)(xb + (size_t)(p0 + cp) * HW + hh * W + col4);
            #pragma unroll
            for (int sx = 0; sx < 3; ++sx) {
                h2 yv[12];
                const _Float16* yr = yt[cur] + (cp * 1360 + (row + sx) * 136 + col4) * 2;
                ((half8*)yv)[0] = *(const half8*)(yr);
                ((half8*)yv)[1] = *(const half8*)(yr + 8);
                ((half8*)yv)[2] = *(const half8*)(yr + 16);
                #pragma unroll
                for (int sy = 0; sy < 9; ++sy)
                    #pragma unroll
                    for (int j = 0; j < 4; ++j)
                        acc[(sx * 9 + sy) * 4 + j] = __builtin_amdgcn_fdot2(
                            x2[j], yv[sy + j], acc[(sx * 9 + sy) * 4 + j], false);
            }
        }
        __syncthreads();
    }

    // epilogue for this chunk's 27 shift planes
    #pragma unroll
    for (int sxl = 0; sxl < 3; ++sxl) {
        int sx = chunk * 3 + sxl;
        float ynv[12];
        const float* yp = ynb + (size_t)(hh + sx) * WP + col4;
        *(floatx4*)&ynv[0] = *(const floatx4*)(yp);
        *(floatx4*)&ynv[4] = *(const floatx4*)(yp + 4);
        *(floatx4*)&ynv[8] = *(const floatx4*)(yp + 8);
        float* ob = out + ((size_t)(b * 24 + brl * 4 + g) * NSHIFT + sx * 9) * HW
                    + hh * W + col4;
        #pragma unroll
        for (int sy = 0; sy < 9; ++sy) {
            float o[4];
            #pragma unroll
            for (int j = 0; j < 4; ++j) {
                float den = xnv[j] * ynv[j + sy];
                den = den > 1e-8f ? den : 1e-8f;
                o[j] = acc[(sxl * 9 + sy) * 4 + j] / den;
            }
            *(floatx4*)(ob + (size_t)sy * HW) = *(floatx4*)o;
        }
    }
}

// ---------------------------------------------------------------------------
extern "C" void kernel_launch(void* const* d_in, const int* in_sizes, int n_in,
                              void* d_out, int out_size, void* d_ws, size_t ws_size,
                              hipStream_t stream) {
    const float* x       = (const float*)d_in[0];
    const float* y       = (const float*)d_in[1];
    const float* weights = (const float*)d_in[2];
    const float* biases  = (const float*)d_in[3];
    float* out = (float*)d_out;

    const size_t ygh_b = (size_t)NBR * B * 4 * 16 * HWP * 4;  // 43,450,368
    const size_t yn_b  = (size_t)NBR * B * 4 * HWP * 4;       //  2,715,648
    const size_t xn_b  = (size_t)B * 4 * HW * 4;              //    393,216
    const size_t yt_b  = (size_t)B * HW * CH * 2;             //  6,291,456
    const size_t wt_b  = (size_t)NBR * 9 * CH * CH * 2;       //  1,769,472
    const size_t xh_b  = (size_t)B * 4 * 16 * HW * 4;         //  6,291,456

    char* p = (char*)d_ws;
    h2* ygh       = (h2*)p;       p += ygh_b;
    float* yn_all = (float*)p;    p += yn_b;
    float* xn     = (float*)p;    p += xn_b;
    _Float16* yt16 = (_Float16*)p; p += yt_b;
    _Float16* w16t = (_Float16*)p; p += wt_b;
    h2* xh        = (h2*)p;       p += xh_b;
    _Float16* zbuf = (_Float16*)p;

    prep_y<<<dim3(HW / 128, B), 256, 0, stream>>>(y, yt16);
    convert_w_kernel<<<(NBR * 9 * CH * CH + 255) / 256, 256, 0, stream>>>(weights, w16t, zbuf);
    prep_x<<<dim3(HW / 256, B), 256, 0, stream>>>(x, xh, xn);

    conv_mfma<<<dim3(NBLK), 256, 0, stream>>>(yt16, w16t, zbuf, biases, ygh, yn_all);

    corr2_kernel<<<dim3(12, 8, NBR * 3), 256, 0, stream>>>(xh, ygh, xn, yn_all, out);
}

// Round 4
// 353.567 us; speedup vs baseline: 1.0080x; 1.0080x over previous
//
#include <hip/hip_runtime.h>
#include <math.h>

#define B 2
#define CH 128
#define H 96
#define W 128
#define HP 104
#define WP 136
#define KPAD 4
#define NSHIFT 81
#define NBR 6
#define HW (H*W)         // 12288
#define HWP (HP*WP)      // 14144
#define NTILE 111        // ceil(14144/128)
#define NWORK (NTILE*12) // 1332
#define NBLK  (8*167)    // 1336 (>= NWORK, 8-way XCD chunking)

typedef _Float16 h2 __attribute__((ext_vector_type(2)));
typedef _Float16 half8 __attribute__((ext_vector_type(8)));
typedef float floatx4 __attribute__((ext_vector_type(4)));

__device__ __constant__ int d_radius[NBR] = {1, 3, 5, 9, 13, 21};

__device__ __forceinline__ void async16(const _Float16* g, _Float16* l) {
    __builtin_amdgcn_global_load_lds(
        (const __attribute__((address_space(1))) unsigned int*)g,
        (__attribute__((address_space(3))) unsigned int*)l, 16, 0, 0);
}

// ---------------------------------------------------------------------------
// y[b][c][hw] (f32) -> yt16[b][hw][c] (f16) channels-last, via LDS transpose.
__global__ __launch_bounds__(256) void prep_y(const float* __restrict__ y,
                                              _Float16* __restrict__ yt16) {
    __shared__ h2 tile[64 * 129];   // [c2][pix], padded stride 129 dwords
    const int tid = threadIdx.x;
    const int b = blockIdx.y;
    const int pix0 = blockIdx.x * 128;
    const int half = tid >> 7;       // 0/1 -> channel half
    const int pl = tid & 127;        // pixel lane

    const float* yb = y + (size_t)b * CH * HW + pix0 + pl;
    #pragma unroll
    for (int k = 0; k < 32; ++k) {
        int c = half * 64 + 2 * k;
        float v0 = yb[(size_t)c * HW];
        float v1 = yb[(size_t)(c + 1) * HW];
        h2 v; v[0] = (_Float16)v0; v[1] = (_Float16)v1;
        tile[(half * 32 + k) * 129 + pl] = v;
    }
    __syncthreads();

    _Float16* ob = yt16 + ((size_t)b * HW + pix0) * CH;
    #pragma unroll
    for (int it = 0; it < 8; ++it) {
        int pix = it * 16 + (tid >> 4);
        int c2b = (tid & 15) * 4;          // h2 index base
        h2 t0 = tile[(c2b + 0) * 129 + pix];
        h2 t1 = tile[(c2b + 1) * 129 + pix];
        h2 t2 = tile[(c2b + 2) * 129 + pix];
        h2 t3 = tile[(c2b + 3) * 129 + pix];
        half8 o;
        o[0] = t0[0]; o[1] = t0[1]; o[2] = t1[0]; o[3] = t1[1];
        o[4] = t2[0]; o[5] = t2[1]; o[6] = t3[0]; o[7] = t3[1];
        *(half8*)(ob + (size_t)pix * CH + (tid & 15) * 8) = o;
    }
}

// weights[br][co][ci][tap] (f32) -> w16t[br][tap][co][ci] (f16); also zero zbuf
__global__ __launch_bounds__(256) void convert_w_kernel(const float* __restrict__ w,
                                                        _Float16* __restrict__ w16t,
                                                        _Float16* __restrict__ zbuf) {
    int gid = blockIdx.x * 256 + threadIdx.x;
    if (gid < 256) zbuf[gid] = (_Float16)0.0f;
    if (gid >= NBR * 9 * CH * CH) return;
    int ci = gid & 127;
    int co = (gid >> 7) & 127;
    int rest = gid >> 14;       // br*9 + tap
    int tap = rest % 9;
    int br = rest / 9;
    w16t[gid] = (_Float16)w[(((size_t)(br * CH + co)) * CH + ci) * 9 + tap];
}

// x[b][c][hw] f32 -> xh[b][g][pair][hw] half2 AND xn[b][g][hw] (fused, 1 pass).
__global__ __launch_bounds__(256) void prep_x(const float* __restrict__ x,
                                              h2* __restrict__ xh,
                                              float* __restrict__ xn) {
    const int b = blockIdx.y;
    const int pix = blockIdx.x * 256 + threadIdx.x;
    const float* xb = x + (size_t)b * CH * HW + pix;
    #pragma unroll
    for (int g = 0; g < 4; ++g) {
        float s = 0.f;
        #pragma unroll
        for (int p = 0; p < 16; ++p) {
            int c = g * 32 + 2 * p;
            float v0 = xb[(size_t)c * HW];
            float v1 = xb[(size_t)(c + 1) * HW];
            h2 v; v[0] = (_Float16)v0; v[1] = (_Float16)v1;
            xh[((size_t)((b * 4 + g) * 16 + p)) * HW + pix] = v;
            s += v0 * v0 + v1 * v1;
        }
        xn[(size_t)(b * 4 + g) * HW + pix] = sqrtf(s);
    }
}

// ---------------------------------------------------------------------------
// Implicit-GEMM dilated conv, f16 MFMA. 128 co x 128 pixels per block.
// Depth-2 counted-vmcnt pipeline (T4) + T2 both-sides XOR swizzle:
//   LDS tile [row][32 halves]; 16-B slot s' stores global slot s'^key(row),
//   key(row) = (row>>1)&3. Applied on the per-lane GLOBAL source (LDS dest of
//   global_load_lds stays linear, rule #21) and identically on the ds_read
//   offset. Turns the 8-way read conflict (64-B row stride, column-slice
//   read) into 2-way (free, m136).
// Writes ygh (bias added) AND fused yn_all.
__global__ __launch_bounds__(256) void conv_mfma(const _Float16* __restrict__ yt16,
                                                 const _Float16* __restrict__ w16t,
                                                 const _Float16* __restrict__ zbuf,
                                                 const float* __restrict__ biases,
                                                 h2* __restrict__ ygh,
                                                 float* __restrict__ yn_all) {
    const int f = blockIdx.x;
    const int Wk = (f & 7) * 167 + (f >> 3);
    if (Wk >= NWORK) return;
    const int tile = Wk / 12;
    const int brb = Wk - tile * 12;
    const int br = brb >> 1;
    const int b = brb & 1;

    const int tid = threadIdx.x;
    const int lane = tid & 63;
    const int wv = tid >> 6;
    const int d = d_radius[br];
    const int px0 = tile * 128;

    __shared__ __align__(16) _Float16 Al[3][128 * 32];
    __shared__ __align__(16) _Float16 Bl[3][128 * 32];

    const int l16 = tid & 3;
    // write-side swizzle key: row = wv*16 + (lane>>2)  =>  (row>>1)&3 = (lane>>3)&3
    const int kw = (lane >> 3) & 3;
    const int wsw = (l16 ^ kw) * 8;     // swizzled 8-half slot offset (source side)

    int ph[2], pw[2];
    bool pval[2];
    #pragma unroll
    for (int s = 0; s < 2; ++s) {
        int pixl = s * 64 + (tid >> 2);
        int pix = px0 + pixl;
        pval[s] = pix < HWP;
        int phh = pix / WP;
        ph[s] = phh; pw[s] = pix - phh * WP;
    }

    const _Float16* ytb = yt16 + (size_t)b * HW * CH;
    const _Float16* wbr = w16t + (size_t)br * 9 * CH * CH;

    floatx4 acc[4][4];
    #pragma unroll
    for (int i = 0; i < 4; i++)
        #pragma unroll
        for (int j = 0; j < 4; j++) {
            floatx4 z = {0.f, 0.f, 0.f, 0.f};
            acc[i][j] = z;
        }

    const int mrow = (wv & 1) * 64 + (lane & 15);
    const int ncol = (wv >> 1) * 64 + (lane & 15);
    // read-side swizzle: row = mrow(+i*16) => key = ((lane&15)>>1)&3; slot = lane>>4
    const int kqs = (((lane >> 4) ^ (((lane & 15) >> 1) & 3))) * 8;

    const _Float16* bt0; const _Float16* bt1;   // B rows for the tap being ISSUED
    auto comp_brow = [&](int tap) {
        const int dkh = (tap / 3 - 1) * d;
        const int dkw = (tap % 3 - 1) * d;
        const _Float16* bw[2];
        #pragma unroll
        for (int s = 0; s < 2; ++s) {
            int gr = ph[s] + dkh, gc = pw[s] + dkw;
            bool v = pval[s] && ((unsigned)gr < (unsigned)HP) && ((unsigned)gc < (unsigned)WP);
            if (v) {
                int yr = gr - KPAD; yr = yr < 0 ? -yr : (yr >= H ? 2 * (H - 1) - yr : yr);
                int yc = gc - KPAD; yc = yc < 0 ? -yc : (yc >= W ? 2 * (W - 1) - yc : yc);
                bw[s] = ytb + ((size_t)(yr * W + yc)) * CH + wsw;
            } else {
                bw[s] = zbuf + wsw;
            }
        }
        bt0 = bw[0]; bt1 = bw[1];
    };

    const _Float16* wa0 = wbr + (tid >> 2) * CH + wsw;
    auto issue = [&](int t, int bufi) {
        const int tap = t >> 2, ck = t & 3;
        const int ci0 = ck * 32;
        const _Float16* wa = wa0 + tap * (CH * CH) + ci0;
        async16(wa,           Al[bufi] + wv * 512);
        async16(wa + 64 * CH, Al[bufi] + 2048 + wv * 512);
        async16(bt0 + ci0,    Bl[bufi] + wv * 512);
        async16(bt1 + ci0,    Bl[bufi] + 2048 + wv * 512);
    };

    auto compute = [&](int bufi) {
        half8 af[4], bf[4];
        #pragma unroll
        for (int i = 0; i < 4; i++) af[i] = *(const half8*)&Al[bufi][(mrow + i * 16) * 32 + kqs];
        #pragma unroll
        for (int j = 0; j < 4; j++) bf[j] = *(const half8*)&Bl[bufi][(ncol + j * 16) * 32 + kqs];
        #pragma unroll
        for (int i = 0; i < 4; i++)
            #pragma unroll
            for (int j = 0; j < 4; j++)
                acc[i][j] = __builtin_amdgcn_mfma_f32_16x16x32_f16(af[i], bf[j], acc[i][j], 0, 0, 0);
    };

    // prologue: issue steps 0 and 1
    comp_brow(0);
    issue(0, 0);
    issue(1, 1);

    int bufc = 0;
    for (int s = 0; s < 35; ++s) {
        asm volatile("s_waitcnt vmcnt(4)" ::: "memory");
        __builtin_amdgcn_s_barrier();
        __builtin_amdgcn_sched_barrier(0);
        const int t2 = s + 2;
        if (t2 < 36) {
            if ((t2 & 3) == 0) comp_brow(t2 >> 2);
            int bn = bufc + 2; if (bn >= 3) bn -= 3;
            issue(t2, bn);
        }
        compute(bufc);
        bufc = (bufc == 2) ? 0 : bufc + 1;
    }
    // last step: drain fully
    asm volatile("s_waitcnt vmcnt(0)" ::: "memory");
    __builtin_amdgcn_s_barrier();
    __builtin_amdgcn_sched_barrier(0);
    compute(bufc);

    // epilogue: bias + pack to half2 pairs. C layout: n=lane&15, m=(lane>>4)*4+reg
    float yna[2][4];
    #pragma unroll
    for (int gs = 0; gs < 2; ++gs)
        #pragma unroll
        for (int j = 0; j < 4; ++j) yna[gs][j] = 0.f;

    #pragma unroll
    for (int i = 0; i < 4; i++) {
        int m0 = (wv & 1) * 64 + i * 16 + (lane >> 4) * 4;   // multiple of 4
        int g0 = (m0 >> 5);
        int pp = (m0 & 31) >> 1;
        float b0 = biases[br * CH + m0];
        float b1 = biases[br * CH + m0 + 1];
        float b2 = biases[br * CH + m0 + 2];
        float b3 = biases[br * CH + m0 + 3];
        h2* outp = ygh + (((size_t)(br * B + b) * 4 + g0) * 16 + pp) * HWP;
        #pragma unroll
        for (int j = 0; j < 4; j++) {
            int pix = px0 + (wv >> 1) * 64 + j * 16 + (lane & 15);
            if (pix < HWP) {
                float f0 = acc[i][j][0] + b0;
                float f1 = acc[i][j][1] + b1;
                float f2 = acc[i][j][2] + b2;
                float f3 = acc[i][j][3] + b3;
                yna[i >> 1][j] += f0 * f0 + f1 * f1 + f2 * f2 + f3 * f3;
                h2 v0, v1;
                v0[0] = (_Float16)f0;
                v0[1] = (_Float16)f1;
                v1[0] = (_Float16)f2;
                v1[1] = (_Float16)f3;
                outp[pix] = v0;
                outp[(size_t)HWP + pix] = v1;
            }
        }
    }

    #pragma unroll
    for (int gs = 0; gs < 2; ++gs) {
        #pragma unroll
        for (int j = 0; j < 4; ++j) {
            float s = yna[gs][j];
            s += __shfl_xor(s, 16);
            s += __shfl_xor(s, 32);
            if ((lane >> 4) == 0) {
                int pix = px0 + (wv >> 1) * 64 + j * 16 + lane;
                if (pix < HWP) {
                    int g = (wv & 1) * 2 + gs;
                    yn_all[((size_t)((br * B + b) * 4 + g)) * HWP + pix] = sqrtf(s);
                }
            }
        }
    }
}

// ---------------------------------------------------------------------------
// Correlation: chunk dim in the grid (1728 blocks), double-buffered staging
// with prefetch-before-compute. Grid: (12, 8, NBR*3)
#define CPAIR 4
__global__ __launch_bounds__(256) void corr2_kernel(const h2* __restrict__ xh,
                                                    const h2* __restrict__ ygh,
                                                    const float* __restrict__ xn,
                                                    const float* __restrict__ yn_all,
                                                    float* __restrict__ out) {
    const int tid = threadIdx.x;
    const int row = tid >> 5;          // 0..7
    const int col4 = (tid & 31) * 4;   // 0..124
    const int H0 = blockIdx.x * 8;
    const int bg = blockIdx.y;
    const int g = bg & 3, b = bg >> 2;
    const int brl = blockIdx.z / 3;
    const int chunk = blockIdx.z - brl * 3;
    const int hh = H0 + row;
    const int row0 = H0 + chunk * 3;

    __shared__ __align__(16) _Float16 yt[2][CPAIR * 340 * 8];   // 2 x 21760 B

    const h2* ygb = ygh + ((size_t)((brl * B + b) * 4 + g) * 16) * HWP;
    const h2* xb  = xh  + ((size_t)(b * 4 + g) * 16) * HW;
    const float* ynb = yn_all + (size_t)((brl * B + b) * 4 + g) * HWP;

    float xnv[4];
    *(floatx4*)xnv = *(const floatx4*)(xn + (size_t)(b * 4 + g) * HW + hh * W + col4);

    float acc[108];
    #pragma unroll
    for (int s = 0; s < 108; ++s) acc[s] = 0.f;

    // prologue: stage pairs [0,CPAIR) into buffer 0
    for (int i = tid; i < CPAIR * 340; i += 256) {
        int pr = i / 340, off = i - pr * 340;
        const _Float16* src =
            (const _Float16*)(ygb + (size_t)pr * HWP + row0 * WP) + off * 8;
        async16(src, yt[0] + i * 8);
    }
    __syncthreads();

    #pragma unroll
    for (int pi = 0; pi < 4; ++pi) {
        const int cur = pi & 1;
        if (pi < 3) {
            const int p0n = (pi + 1) * CPAIR;
            for (int i = tid; i < CPAIR * 340; i += 256) {
                int pr = i / 340, off = i - pr * 340;
                const _Float16* src =
                    (const _Float16*)(ygb + (size_t)(p0n + pr) * HWP + row0 * WP) + off * 8;
                async16(src, yt[cur ^ 1] + i * 8);
            }
        }
        const int p0 = pi * CPAIR;
        #pragma unroll
        for (int cp = 0; cp < CPAIR; ++cp) {
            h2 x2[4];
            *(half8*)x2 = *(const half8*)(xb + (size_t)(p0 + cp) * HW + hh * W + col4);
            #pragma unroll
            for (int sx = 0; sx < 3; ++sx) {
                h2 yv[12];
                const _Float16* yr = yt[cur] + (cp * 1360 + (row + sx) * 136 + col4) * 2;
                ((half8*)yv)[0] = *(const half8*)(yr);
                ((half8*)yv)[1] = *(const half8*)(yr + 8);
                ((half8*)yv)[2] = *(const half8*)(yr + 16);
                #pragma unroll
                for (int sy = 0; sy < 9; ++sy)
                    #pragma unroll
                    for (int j = 0; j < 4; ++j)
                        acc[(sx * 9 + sy) * 4 + j] = __builtin_amdgcn_fdot2(
                            x2[j], yv[sy + j], acc[(sx * 9 + sy) * 4 + j], false);
            }
        }
        __syncthreads();
    }

    // epilogue for this chunk's 27 shift planes
    #pragma unroll
    for (int sxl = 0; sxl < 3; ++sxl) {
        int sx = chunk * 3 + sxl;
        float ynv[12];
        const float* yp = ynb + (size_t)(hh + sx) * WP + col4;
        *(floatx4*)&ynv[0] = *(const floatx4*)(yp);
        *(floatx4*)&ynv[4] = *(const floatx4*)(yp + 4);
        *(floatx4*)&ynv[8] = *(const floatx4*)(yp + 8);
        float* ob = out + ((size_t)(b * 24 + brl * 4 + g) * NSHIFT + sx * 9) * HW
                    + hh * W + col4;
        #pragma unroll
        for (int sy = 0; sy < 9; ++sy) {
            float o[4];
            #pragma unroll
            for (int j = 0; j < 4; ++j) {
                float den = xnv[j] * ynv[j + sy];
                den = den > 1e-8f ? den : 1e-8f;
                o[j] = acc[(sxl * 9 + sy) * 4 + j] / den;
            }
            *(floatx4*)(ob + (size_t)sy * HW) = *(floatx4*)o;
        }
    }
}

// ---------------------------------------------------------------------------
extern "C" void kernel_launch(void* const* d_in, const int* in_sizes, int n_in,
                              void* d_out, int out_size, void* d_ws, size_t ws_size,
                              hipStream_t stream) {
    const float* x       = (const float*)d_in[0];
    const float* y       = (const float*)d_in[1];
    const float* weights = (const float*)d_in[2];
    const float* biases  = (const float*)d_in[3];
    float* out = (float*)d_out;

    const size_t ygh_b = (size_t)NBR * B * 4 * 16 * HWP * 4;  // 43,450,368
    const size_t yn_b  = (size_t)NBR * B * 4 * HWP * 4;       //  2,715,648
    const size_t xn_b  = (size_t)B * 4 * HW * 4;              //    393,216
    const size_t yt_b  = (size_t)B * HW * CH * 2;             //  6,291,456
    const size_t wt_b  = (size_t)NBR * 9 * CH * CH * 2;       //  1,769,472
    const size_t xh_b  = (size_t)B * 4 * 16 * HW * 4;         //  6,291,456

    char* p = (char*)d_ws;
    h2* ygh       = (h2*)p;       p += ygh_b;
    float* yn_all = (float*)p;    p += yn_b;
    float* xn     = (float*)p;    p += xn_b;
    _Float16* yt16 = (_Float16*)p; p += yt_b;
    _Float16* w16t = (_Float16*)p; p += wt_b;
    h2* xh        = (h2*)p;       p += xh_b;
    _Float16* zbuf = (_Float16*)p;

    prep_y<<<dim3(HW / 128, B), 256, 0, stream>>>(y, yt16);
    convert_w_kernel<<<(NBR * 9 * CH * CH + 255) / 256, 256, 0, stream>>>(weights, w16t, zbuf);
    prep_x<<<dim3(HW / 256, B), 256, 0, stream>>>(x, xh, xn);

    conv_mfma<<<dim3(NBLK), 256, 0, stream>>>(yt16, w16t, zbuf, biases, ygh, yn_all);

    corr2_kernel<<<dim3(12, 8, NBR * 3), 256, 0, stream>>>(xh, ygh, xn, yn_all, out);
}